// Round 5
// baseline (317.586 us; speedup 1.0000x reference)
//
#include <hip/hip_runtime.h>
#include <stdint.h>

typedef unsigned short u16;
typedef unsigned int u32;

using bf16x8 = __attribute__((ext_vector_type(8))) short;
using f32x4  = __attribute__((ext_vector_type(4))) float;

#define DEVINL __device__ __forceinline__

DEVINL float b2f(u16 u) { return __builtin_bit_cast(float, (u32)u << 16); }
DEVINL u16 f2b(float f) {
  u32 u = __builtin_bit_cast(u32, f);
  u += 0x7FFFu + ((u >> 16) & 1u);   // round-to-nearest-even
  return (u16)(u >> 16);
}

DEVINL void gll16(const u16* src, u16* dst) {
  __builtin_amdgcn_global_load_lds(
      (const __attribute__((address_space(1))) void*)(uintptr_t)src,
      (__attribute__((address_space(3))) void*)(uintptr_t)dst, 16, 0, 0);
}

// ---------------------------------------------------------------- fused convert+transpose
DEVINL void tp_tile(const float* __restrict__ s, u16* __restrict__ d,
                    int R, int C, int bx, int by, int z)
{
  __shared__ u16 tile[32][33];
  const size_t mstride = (size_t)R * C;
  s += (size_t)z * mstride;
  d += (size_t)z * mstride;
  int r0 = bx * 32, c0 = by * 32;
  int tx = threadIdx.x & 31, ty = threadIdx.x >> 5;
#pragma unroll
  for (int i = 0; i < 32; i += 8)
    tile[ty + i][tx] = f2b(s[(size_t)(r0 + ty + i) * C + (c0 + tx)]);
  __syncthreads();
#pragma unroll
  for (int i = 0; i < 32; i += 8)
    d[(size_t)(c0 + ty + i) * R + (r0 + tx)] = tile[tx][ty + i];
}

__global__ __launch_bounds__(256) void transpose_all(
    const float* W0, const float* W1, const float* Wr0, const float* Wr1, const float* Wh0,
    u16* W0t, u16* W1t, u16* Wr0t, u16* Wr1t, u16* Wh0t)
{
  int b = blockIdx.x;
  if (b < 128)      {            tp_tile(W0, W0t, 256, 512, b % 8,  b / 8, 0); }
  else if (b < 384) { b -= 128;  tp_tile(W1, W1t, 512, 512, b % 16, b / 16, 0); }
  else if (b < 576) { b -= 384;  int t = b / 8;  tp_tile(Wr0, Wr0t, 256, 128, b % 8,  t % 4,  t / 4); }
  else if (b < 960) { b -= 576;  int t = b / 4;  tp_tile(Wr1, Wr1t, 128, 512, b % 4,  t % 16, t / 16); }
  else              { b -= 960;  int t = b / 16; tp_tile(Wh0, Wh0t, 512, 64,  b % 16, t % 2,  t / 2); }
}

// ---------------------------------------------------------------- obs layernorm (f32 in, bf16 out)
__global__ __launch_bounds__(256) void ln_f32_256(
    const float* __restrict__ X, const float* __restrict__ sc,
    const float* __restrict__ bi, u16* __restrict__ Y, int nrows)
{
  constexpr int D = 256, PER = 4;
  int lane = threadIdx.x & 63;
  int row = blockIdx.x * 4 + (threadIdx.x >> 6);
  if (row >= nrows) return;
  const float* xr = X + (size_t)row * D + lane * PER;
  float x[PER] __attribute__((aligned(16)));
  *(float4*)x = *(const float4*)xr;
  float s = 0.f, s2 = 0.f;
#pragma unroll
  for (int p = 0; p < PER; ++p) { s += x[p]; s2 += x[p] * x[p]; }
#pragma unroll
  for (int o = 32; o > 0; o >>= 1) { s += __shfl_xor(s, o, 64); s2 += __shfl_xor(s2, o, 64); }
  float m = s * (1.f / D);
  float v = s2 * (1.f / D) - m * m;
  float inv = rsqrtf(v + 1e-5f);
  u16 yu[PER] __attribute__((aligned(8)));
#pragma unroll
  for (int p = 0; p < PER; ++p)
    yu[p] = f2b((x[p] - m) * inv * sc[lane * PER + p] + bi[lane * PER + p]);
  *(uint2*)(Y + (size_t)row * D + lane * PER) = *(uint2*)yu;
}

// ---------------------------------------------------------------- role bucketing
#define NROLE 6
__global__ __launch_bounds__(256) void role_count(
    const int* __restrict__ rid, int* __restrict__ blkCnt)
{
  __shared__ int h[NROLE];
  if (threadIdx.x < NROLE) h[threadIdx.x] = 0;
  __syncthreads();
  int i = blockIdx.x * 256 + threadIdx.x;
  atomicAdd(&h[rid[i]], 1);
  __syncthreads();
  if (threadIdx.x < NROLE) blkCnt[blockIdx.x * NROLE + threadIdx.x] = h[threadIdx.x];
}

__global__ __launch_bounds__(256) void role_scan(
    const int* __restrict__ blkCnt, int* __restrict__ blkBase,
    int* __restrict__ baseArr, int* __restrict__ cntArr)
{
  __shared__ int c[128 * NROLE];
  __shared__ int bb[128 * NROLE];
  __shared__ int sbase[NROLE], scnt[NROLE];
  for (int i = threadIdx.x; i < 128 * NROLE; i += 256) c[i] = blkCnt[i];
  __syncthreads();
  if (threadIdx.x < NROLE) {
    int k = threadIdx.x, run = 0;
    for (int b = 0; b < 128; ++b) { bb[b * NROLE + k] = run; run += c[b * NROLE + k]; }
    scnt[k] = run;
  }
  __syncthreads();
  if (threadIdx.x == 0) {
    int r = 0;
    for (int k = 0; k < NROLE; ++k) { sbase[k] = r; r += scnt[k]; }
  }
  __syncthreads();
  if (threadIdx.x < NROLE) { baseArr[threadIdx.x] = sbase[threadIdx.x]; cntArr[threadIdx.x] = scnt[threadIdx.x]; }
  for (int i = threadIdx.x; i < 128 * NROLE; i += 256)
    blkBase[i] = bb[i] + sbase[i % NROLE];
}

__global__ __launch_bounds__(256) void role_fill(
    const int* __restrict__ rid, const int* __restrict__ blkBase, int* __restrict__ bucket)
{
  __shared__ int h[NROLE];
  if (threadIdx.x < NROLE) h[threadIdx.x] = 0;
  __syncthreads();
  int i = blockIdx.x * 256 + threadIdx.x;
  int k = rid[i];
  int pos = atomicAdd(&h[k], 1);
  bucket[blkBase[blockIdx.x * NROLE + k] + pos] = i;
}

// ---------------------------------------------------------------- fused dense GEMM + ReLU + LN
// C[M x 512] = LN(relu(A[M x K] @ Bt[512 x K]^T + bias)). BM=32, 256 thr,
// 4 waves x 128 cols, acc[2][8]. A via LDS (swizzled), B direct from global (L2-hot).
// grid = 1024 blocks -> 4 blocks/CU.
template <int K>
__global__ __launch_bounds__(256, 4) void gemm_ln(
    const u16* __restrict__ A, const u16* __restrict__ Bt,
    const float* __restrict__ bias, const float* __restrict__ lnsc,
    const float* __restrict__ lnbi, u16* __restrict__ C)
{
  constexpr int BK = 64;
  __shared__ __align__(16) u16 As[32 * BK];       // 4 KB
  __shared__ float redS[32][4];
  __shared__ float redSS[32][4];
  __shared__ float prm[1536];                     // bias | sc | bi
  const int tid = threadIdx.x;
  const int rowBase = blockIdx.x * 32;
  const int lane = tid & 63, wave = tid >> 6;
#pragma unroll
  for (int i = tid; i < 512; i += 256) {
    prm[i] = bias[i]; prm[512 + i] = lnsc[i]; prm[1024 + i] = lnbi[i];
  }
  const int srow = tid >> 3;
  const u32 aOff = (u32)(rowBase + srow) * (u32)K + (u32)(((tid & 7) ^ (srow & 7)) * 8);
  const int quad = lane >> 4, lm = lane & 15, l7 = lm & 7;
  const int wn = wave * 128;
  u32 bOff[8];
#pragma unroll
  for (int j = 0; j < 8; ++j)
    bOff[j] = (u32)(wn + j * 16 + lm) * (u32)K + (u32)(quad * 8);

  f32x4 acc[2][8] = {};

  for (int k0 = 0; k0 < K; k0 += BK) {
    gll16(A + aOff + k0, &As[wave * 512]);
    __syncthreads();
#pragma unroll
    for (int kk = 0; kk < BK; kk += 32) {
      const int kc = kk >> 3;
      bf16x8 af[2], bfr[8];
#pragma unroll
      for (int i2 = 0; i2 < 2; ++i2)
        af[i2] = *(const bf16x8*)&As[(i2 * 16 + lm) * 64 + (((quad + kc) ^ l7) * 8)];
#pragma unroll
      for (int j = 0; j < 8; ++j)
        bfr[j] = *(const bf16x8*)(Bt + bOff[j] + k0 + kk);
#pragma unroll
      for (int i2 = 0; i2 < 2; ++i2)
#pragma unroll
        for (int j = 0; j < 8; ++j)
          acc[i2][j] = __builtin_amdgcn_mfma_f32_16x16x32_bf16(af[i2], bfr[j], acc[i2][j], 0, 0, 0);
    }
    __syncthreads();
  }

  // bias + relu + per-row partial stats
#pragma unroll
  for (int i2 = 0; i2 < 2; ++i2) {
#pragma unroll
    for (int r2 = 0; r2 < 4; ++r2) {
      float s = 0.f, ss = 0.f;
#pragma unroll
      for (int j = 0; j < 8; ++j) {
        float v = fmaxf(acc[i2][j][r2] + prm[wn + j * 16 + lm], 0.f);
        acc[i2][j][r2] = v;
        s += v; ss += v * v;
      }
#pragma unroll
      for (int o = 1; o < 16; o <<= 1) { s += __shfl_xor(s, o, 64); ss += __shfl_xor(ss, o, 64); }
      if (lm == 0) {
        int rowL = i2 * 16 + quad * 4 + r2;
        redS[rowL][wave] = s;
        redSS[rowL][wave] = ss;
      }
    }
  }
  __syncthreads();
#pragma unroll
  for (int i2 = 0; i2 < 2; ++i2) {
#pragma unroll
    for (int r2 = 0; r2 < 4; ++r2) {
      int rowL = i2 * 16 + quad * 4 + r2;
      float ts  = redS[rowL][0] + redS[rowL][1] + redS[rowL][2] + redS[rowL][3];
      float tss = redSS[rowL][0] + redSS[rowL][1] + redSS[rowL][2] + redSS[rowL][3];
      float m = ts * (1.f / 512.f);
      float var = tss * (1.f / 512.f) - m * m;
      float inv = rsqrtf(var + 1e-5f);
      size_t base = (size_t)(rowBase + rowL) * 512;
#pragma unroll
      for (int j = 0; j < 8; ++j) {
        int col = wn + j * 16 + lm;
        float y = (acc[i2][j][r2] - m) * inv * prm[512 + col] + prm[1024 + col];
        C[base + col] = f2b(y);
      }
    }
  }
}

// ---------------------------------------------------------------- fused role route + head0
// Per 32-row bucket tile: r1 = relu(obs_n[g] @ Wr0k + br0)      (K=256 -> 128)
//                         ea = relu(r1 @ Wr1k + br1) + e[g]     (K=128 -> 512)
//                         h0 = relu(ea @ Wh0k + bh0)            (K=512 -> 64) -> h0buf
// Intermediates in LDS with XOR chunk swizzle; B ops direct from global (L2-hot).
__global__ __launch_bounds__(256, 3) void route_head(
    const u16* __restrict__ obs_n, const u16* __restrict__ e,
    const u16* __restrict__ Wr0t, const float* __restrict__ br0,
    const u16* __restrict__ Wr1t, const float* __restrict__ br1,
    const u16* __restrict__ Wh0t, const float* __restrict__ bh0,
    const int* __restrict__ bucket, const int* __restrict__ baseArr,
    const int* __restrict__ cntArr, u16* __restrict__ h0buf)
{
  // sm layout: [0,8192) A0 (32x256)  -- later reused as [0,16384) e-tile (32x512)
  //            [16384, 20480) r1 (32x128)
  __shared__ __align__(16) u16 sm[20480];
  __shared__ float prm[704];   // br0 128 | br1 512 | bh0 64
  const int tid = threadIdx.x;

  int role = 0, rem = blockIdx.x, cnt;
  for (;;) {
    cnt = cntArr[role];
    int tiles = (cnt + 31) >> 5;
    if (rem < tiles) break;
    rem -= tiles;
    if (++role >= NROLE) return;
  }
  const int limit = cnt;
  const int rowBase = rem * 32;
  const int roleBase = baseArr[role];

  {
    const float* s0 = br0 + role * 128;
    const float* s1 = br1 + role * 512;
    const float* s2 = bh0 + role * 64;
    if (tid < 128) prm[tid] = s0[tid];
    for (int i = tid; i < 512; i += 256) prm[128 + i] = s1[i];
    if (tid < 64) prm[640 + tid] = s2[tid];
  }

  const int lane = tid & 63, wave = tid >> 6;
  const int quad = lane >> 4, lm = lane & 15, l7 = lm & 7;

  // ---- stage A0: gather 32 rows of obs_n (32x256) into LDS
#pragma unroll
  for (int r = 0; r < 4; ++r) {
    int lrow = r * 8 + (tid >> 5);
    int i = rowBase + lrow;
    if (i >= limit) i = rowBase;
    int grow = bucket[roleBase + i];
    gll16(obs_n + (u32)grow * 256u + (u32)((((tid & 31) ^ (lrow & 7)) * 8)),
          &sm[r * 2048 + wave * 512]);
  }
  __syncthreads();

  // ---- stage0: r1 = relu(A0 @ Wr0k^T + br0)   (N=128, wave covers 32 cols)
  const int wn0 = wave * 32;
  const u16* B0 = Wr0t + (size_t)role * 128 * 256;
  f32x4 acc0[2][2] = {};
#pragma unroll
  for (int kk = 0; kk < 256; kk += 32) {
    const int kc = kk >> 3;
    bf16x8 af[2], bf0[2];
#pragma unroll
    for (int i2 = 0; i2 < 2; ++i2)
      af[i2] = *(const bf16x8*)&sm[(i2 * 16 + lm) * 256 + (((quad + kc) ^ l7) * 8)];
#pragma unroll
    for (int j = 0; j < 2; ++j)
      bf0[j] = *(const bf16x8*)(B0 + (u32)(wn0 + j * 16 + lm) * 256u + (u32)(quad * 8 + kk));
#pragma unroll
    for (int i2 = 0; i2 < 2; ++i2)
#pragma unroll
      for (int j = 0; j < 2; ++j)
        acc0[i2][j] = __builtin_amdgcn_mfma_f32_16x16x32_bf16(af[i2], bf0[j], acc0[i2][j], 0, 0, 0);
  }
  u16* r1 = sm + 16384;
#pragma unroll
  for (int i2 = 0; i2 < 2; ++i2) {
#pragma unroll
    for (int r2 = 0; r2 < 4; ++r2) {
      int row = i2 * 16 + quad * 4 + r2;
#pragma unroll
      for (int j = 0; j < 2; ++j) {
        int col = wn0 + j * 16 + lm;
        float v = fmaxf(acc0[i2][j][r2] + prm[col], 0.f);
        r1[row * 128 + (((col >> 3) ^ (row & 7)) * 8) + (col & 7)] = f2b(v);
      }
    }
  }
  __syncthreads();

  // ---- stage1: ea = relu(r1 @ Wr1k^T + br1) + e[g]   (N=512, wave covers 128 cols)
  const int wn1 = wave * 128;
  const u16* B1 = Wr1t + (size_t)role * 512 * 128;
  f32x4 acc1[2][8] = {};
#pragma unroll
  for (int kk = 0; kk < 128; kk += 32) {
    const int kc = kk >> 3;
    bf16x8 af[2], bf1[8];
#pragma unroll
    for (int i2 = 0; i2 < 2; ++i2)
      af[i2] = *(const bf16x8*)&r1[(i2 * 16 + lm) * 128 + (((quad + kc) ^ l7) * 8)];
#pragma unroll
    for (int j = 0; j < 8; ++j)
      bf1[j] = *(const bf16x8*)(B1 + (u32)(wn1 + j * 16 + lm) * 128u + (u32)(quad * 8 + kk));
#pragma unroll
    for (int i2 = 0; i2 < 2; ++i2)
#pragma unroll
      for (int j = 0; j < 8; ++j)
        acc1[i2][j] = __builtin_amdgcn_mfma_f32_16x16x32_bf16(af[i2], bf1[j], acc1[i2][j], 0, 0, 0);
  }
#pragma unroll
  for (int i2 = 0; i2 < 2; ++i2) {
#pragma unroll
    for (int r2 = 0; r2 < 4; ++r2) {
      int row = i2 * 16 + quad * 4 + r2;
      int i = rowBase + row;
      int ic = (i < limit) ? i : (limit - 1);
      u32 grow = (u32)bucket[roleBase + ic];
#pragma unroll
      for (int j = 0; j < 8; ++j) {
        int col = wn1 + j * 16 + lm;
        float v = fmaxf(acc1[i2][j][r2] + prm[128 + col], 0.f) + b2f(e[(size_t)grow * 512 + col]);
        sm[row * 512 + (((col >> 3) ^ (row & 7)) * 8) + (col & 7)] = f2b(v);
      }
    }
  }
  __syncthreads();

  // ---- stage2: h0 = relu(ea @ Wh0k^T + bh0)   (N=64, wave covers 16 cols)
  const int wn2 = wave * 16;
  const u16* B2 = Wh0t + (size_t)role * 64 * 512;
  f32x4 acc2[2] = {};
#pragma unroll
  for (int kk = 0; kk < 512; kk += 32) {
    const int kc = kk >> 3;
    bf16x8 af[2], bf2;
#pragma unroll
    for (int i2 = 0; i2 < 2; ++i2)
      af[i2] = *(const bf16x8*)&sm[(i2 * 16 + lm) * 512 + (((quad + kc) ^ l7) * 8)];
    bf2 = *(const bf16x8*)(B2 + (u32)(wn2 + lm) * 512u + (u32)(quad * 8 + kk));
#pragma unroll
    for (int i2 = 0; i2 < 2; ++i2)
      acc2[i2] = __builtin_amdgcn_mfma_f32_16x16x32_bf16(af[i2], bf2, acc2[i2], 0, 0, 0);
  }
#pragma unroll
  for (int i2 = 0; i2 < 2; ++i2) {
#pragma unroll
    for (int r2 = 0; r2 < 4; ++r2) {
      int row = i2 * 16 + quad * 4 + r2;
      int i = rowBase + row;
      if (i >= limit) continue;
      int col = wn2 + lm;
      float v = fmaxf(acc2[i2][r2] + prm[640 + col], 0.f);
      h0buf[(size_t)(roleBase + i) * 64 + col] = f2b(v);
    }
  }
}

// ---------------------------------------------------------------- head tail
__global__ __launch_bounds__(256) void head_tail(
    const u16* __restrict__ h0buf, const int* __restrict__ bucket,
    const int* __restrict__ baseArr,
    const float* __restrict__ Wh1, const float* __restrict__ bh1,
    const float* __restrict__ Wh2, const float* __restrict__ bh2,
    const float* __restrict__ avail, float* __restrict__ outLogits)
{
  int lane = threadIdx.x & 63;
  int p = blockIdx.x * 4 + (threadIdx.x >> 6);
  int row = bucket[p];
  int k = 0;
#pragma unroll
  for (int j = 1; j < NROLE; ++j) k += (p >= baseArr[j]);
  float h0 = b2f(h0buf[(size_t)p * 64 + lane]);
  int n = lane & 31, half = lane >> 5;
  const float* W1k = Wh1 + k * 64 * 32;
  float a1 = 0.f;
#pragma unroll
  for (int jj = 0; jj < 32; ++jj) {
    int j = half * 32 + jj;
    float hj = __shfl(h0, j, 64);
    a1 += hj * W1k[j * 32 + n];
  }
  a1 += __shfl_xor(a1, 32, 64);
  float h1 = fmaxf(a1 + bh1[k * 32 + n], 0.f);
  const float* W2k = Wh2 + k * 32 * 32;
  float a2 = 0.f;
#pragma unroll
  for (int nn = 0; nn < 32; ++nn) {
    float hn = __shfl(h1, nn, 64);
    a2 += hn * W2k[nn * 32 + n];
  }
  float logit = a2 + bh2[k * 32 + n];
  float av = avail[(size_t)row * 32 + n];
  if (av <= 0.5f) logit = -1e10f;
  if (half == 0) outLogits[(size_t)row * 32 + n] = logit;
}

// ---------------------------------------------------------------- launcher
extern "C" void kernel_launch(void* const* d_in, const int* in_sizes, int n_in,
                              void* d_out, int out_size, void* d_ws, size_t ws_size,
                              hipStream_t stream)
{
  const float* rnn  = (const float*)d_in[0];
  const float* obs  = (const float*)d_in[1];
  const float* avail= (const float*)d_in[3];
  const int*   rid  = (const int*)d_in[4];
  const float* fn_s = (const float*)d_in[5];
  const float* fn_b = (const float*)d_in[6];
  const float* W0   = (const float*)d_in[7];
  const float* b0   = (const float*)d_in[8];
  const float* ln0s = (const float*)d_in[9];
  const float* ln0b = (const float*)d_in[10];
  const float* W1   = (const float*)d_in[11];
  const float* b1   = (const float*)d_in[12];
  const float* ln1s = (const float*)d_in[13];
  const float* ln1b = (const float*)d_in[14];
  const float* Wr0  = (const float*)d_in[15];
  const float* br0  = (const float*)d_in[16];
  const float* Wr1  = (const float*)d_in[17];
  const float* br1  = (const float*)d_in[18];
  const float* Wh0  = (const float*)d_in[19];
  const float* bh0  = (const float*)d_in[20];
  const float* Wh1  = (const float*)d_in[21];
  const float* bh1  = (const float*)d_in[22];
  const float* Wh2  = (const float*)d_in[23];
  const float* bh2  = (const float*)d_in[24];

  const int ROWS = 32768;

  char* w = (char*)d_ws;
  auto carve = [&](size_t bytes) { char* p = w; w += (bytes + 255) & ~(size_t)255; return p; };
  u16* obs_n  = (u16*)carve((size_t)ROWS * 256 * 2);
  u16* bufA   = (u16*)carve((size_t)ROWS * 512 * 2);   // e0
  u16* bufB   = (u16*)carve((size_t)ROWS * 512 * 2);   // e
  u16* h0buf  = (u16*)carve((size_t)ROWS * 64 * 2);
  u16* W0t    = (u16*)carve((size_t)512 * 256 * 2);
  u16* W1t    = (u16*)carve((size_t)512 * 512 * 2);
  u16* Wr0t   = (u16*)carve((size_t)6 * 128 * 256 * 2);
  u16* Wr1t   = (u16*)carve((size_t)6 * 512 * 128 * 2);
  u16* Wh0t   = (u16*)carve((size_t)6 * 64 * 512 * 2);
  int* bucket = (int*)carve((size_t)ROWS * 4);
  int* blkCnt = (int*)carve((size_t)128 * NROLE * 4);
  int* blkBase= (int*)carve((size_t)128 * NROLE * 4);
  int* baseArr= (int*)carve(256);
  int* cntArr = (int*)carve(256);

  float* outLogits = (float*)d_out + (size_t)1024 * 512;

  hipMemcpyAsync(d_out, rnn, (size_t)1024 * 512 * 4, hipMemcpyDeviceToDevice, stream);

  transpose_all<<<1152, 256, 0, stream>>>(W0, W1, Wr0, Wr1, Wh0, W0t, W1t, Wr0t, Wr1t, Wh0t);

  ln_f32_256<<<8192, 256, 0, stream>>>(obs, fn_s, fn_b, obs_n, ROWS);

  role_count<<<128, 256, 0, stream>>>(rid, blkCnt);
  role_scan<<<1, 256, 0, stream>>>(blkCnt, blkBase, baseArr, cntArr);
  role_fill<<<128, 256, 0, stream>>>(rid, blkBase, bucket);

  // base MLP, LN fused; grid 1024 -> 4 blocks/CU
  gemm_ln<256><<<1024, 256, 0, stream>>>(obs_n, W0t, b0, ln0s, ln0b, bufA);
  gemm_ln<512><<<1024, 256, 0, stream>>>(bufA, W1t, b1, ln1s, ln1b, bufB);

  // fused role route + head0 (max tiles = 1024 + 5)
  route_head<<<1029, 256, 0, stream>>>(obs_n, bufB, Wr0t, br0, Wr1t, br1, Wh0t, bh0,
                                       bucket, baseArr, cntArr, h0buf);

  head_tail<<<8192, 256, 0, stream>>>(h0buf, bucket, baseArr, Wh1, bh1, Wh2, bh2, avail, outLogits);
}

// Round 6
// 274.581 us; speedup vs baseline: 1.1566x; 1.1566x over previous
//
#include <hip/hip_runtime.h>
#include <stdint.h>

typedef unsigned short u16;
typedef unsigned int u32;

using bf16x8 = __attribute__((ext_vector_type(8))) short;
using f32x4  = __attribute__((ext_vector_type(4))) float;

#define DEVINL __device__ __forceinline__

DEVINL float b2f(u16 u) { return __builtin_bit_cast(float, (u32)u << 16); }
DEVINL u16 f2b(float f) {
  u32 u = __builtin_bit_cast(u32, f);
  u += 0x7FFFu + ((u >> 16) & 1u);   // round-to-nearest-even
  return (u16)(u >> 16);
}

DEVINL void gll16(const u16* src, u16* dst) {
  __builtin_amdgcn_global_load_lds(
      (const __attribute__((address_space(1))) void*)(uintptr_t)src,
      (__attribute__((address_space(3))) void*)(uintptr_t)dst, 16, 0, 0);
}

// ---------------------------------------------------------------- fused convert+transpose
DEVINL void tp_tile(const float* __restrict__ s, u16* __restrict__ d,
                    int R, int C, int bx, int by, int z)
{
  __shared__ u16 tile[32][33];
  const size_t mstride = (size_t)R * C;
  s += (size_t)z * mstride;
  d += (size_t)z * mstride;
  int r0 = bx * 32, c0 = by * 32;
  int tx = threadIdx.x & 31, ty = threadIdx.x >> 5;
#pragma unroll
  for (int i = 0; i < 32; i += 8)
    tile[ty + i][tx] = f2b(s[(size_t)(r0 + ty + i) * C + (c0 + tx)]);
  __syncthreads();
#pragma unroll
  for (int i = 0; i < 32; i += 8)
    d[(size_t)(c0 + ty + i) * R + (r0 + tx)] = tile[tx][ty + i];
}

__global__ __launch_bounds__(256) void transpose_all(
    const float* W0, const float* W1, const float* Wr0, const float* Wr1, const float* Wh0,
    u16* W0t, u16* W1t, u16* Wr0t, u16* Wr1t, u16* Wh0t)
{
  int b = blockIdx.x;
  if (b < 128)      {            tp_tile(W0, W0t, 256, 512, b % 8,  b / 8, 0); }
  else if (b < 384) { b -= 128;  tp_tile(W1, W1t, 512, 512, b % 16, b / 16, 0); }
  else if (b < 576) { b -= 384;  int t = b / 8;  tp_tile(Wr0, Wr0t, 256, 128, b % 8,  t % 4,  t / 4); }
  else if (b < 960) { b -= 576;  int t = b / 4;  tp_tile(Wr1, Wr1t, 128, 512, b % 4,  t % 16, t / 16); }
  else              { b -= 960;  int t = b / 16; tp_tile(Wh0, Wh0t, 512, 64,  b % 16, t % 2,  t / 2); }
}

// ---------------------------------------------------------------- obs layernorm (f32 in, bf16 out)
__global__ __launch_bounds__(256) void ln_f32_256(
    const float* __restrict__ X, const float* __restrict__ sc,
    const float* __restrict__ bi, u16* __restrict__ Y, int nrows)
{
  constexpr int D = 256, PER = 4;
  int lane = threadIdx.x & 63;
  int row = blockIdx.x * 4 + (threadIdx.x >> 6);
  if (row >= nrows) return;
  const float* xr = X + (size_t)row * D + lane * PER;
  float x[PER] __attribute__((aligned(16)));
  *(float4*)x = *(const float4*)xr;
  float s = 0.f, s2 = 0.f;
#pragma unroll
  for (int p = 0; p < PER; ++p) { s += x[p]; s2 += x[p] * x[p]; }
#pragma unroll
  for (int o = 32; o > 0; o >>= 1) { s += __shfl_xor(s, o, 64); s2 += __shfl_xor(s2, o, 64); }
  float m = s * (1.f / D);
  float v = s2 * (1.f / D) - m * m;
  float inv = rsqrtf(v + 1e-5f);
  u16 yu[PER] __attribute__((aligned(8)));
#pragma unroll
  for (int p = 0; p < PER; ++p)
    yu[p] = f2b((x[p] - m) * inv * sc[lane * PER + p] + bi[lane * PER + p]);
  *(uint2*)(Y + (size_t)row * D + lane * PER) = *(uint2*)yu;
}

// ---------------------------------------------------------------- role bucketing
#define NROLE 6
__global__ __launch_bounds__(256) void role_count(
    const int* __restrict__ rid, int* __restrict__ blkCnt)
{
  __shared__ int h[NROLE];
  if (threadIdx.x < NROLE) h[threadIdx.x] = 0;
  __syncthreads();
  int i = blockIdx.x * 256 + threadIdx.x;
  atomicAdd(&h[rid[i]], 1);
  __syncthreads();
  if (threadIdx.x < NROLE) blkCnt[blockIdx.x * NROLE + threadIdx.x] = h[threadIdx.x];
}

__global__ __launch_bounds__(256) void role_scan(
    const int* __restrict__ blkCnt, int* __restrict__ blkBase,
    int* __restrict__ baseArr, int* __restrict__ cntArr)
{
  __shared__ int c[128 * NROLE];
  __shared__ int bb[128 * NROLE];
  __shared__ int sbase[NROLE], scnt[NROLE];
  for (int i = threadIdx.x; i < 128 * NROLE; i += 256) c[i] = blkCnt[i];
  __syncthreads();
  if (threadIdx.x < NROLE) {
    int k = threadIdx.x, run = 0;
    for (int b = 0; b < 128; ++b) { bb[b * NROLE + k] = run; run += c[b * NROLE + k]; }
    scnt[k] = run;
  }
  __syncthreads();
  if (threadIdx.x == 0) {
    int r = 0;
    for (int k = 0; k < NROLE; ++k) { sbase[k] = r; r += scnt[k]; }
  }
  __syncthreads();
  if (threadIdx.x < NROLE) { baseArr[threadIdx.x] = sbase[threadIdx.x]; cntArr[threadIdx.x] = scnt[threadIdx.x]; }
  for (int i = threadIdx.x; i < 128 * NROLE; i += 256)
    blkBase[i] = bb[i] + sbase[i % NROLE];
}

__global__ __launch_bounds__(256) void role_fill(
    const int* __restrict__ rid, const int* __restrict__ blkBase, int* __restrict__ bucket)
{
  __shared__ int h[NROLE];
  if (threadIdx.x < NROLE) h[threadIdx.x] = 0;
  __syncthreads();
  int i = blockIdx.x * 256 + threadIdx.x;
  int k = rid[i];
  int pos = atomicAdd(&h[k], 1);
  bucket[blkBase[blockIdx.x * NROLE + k] + pos] = i;
}

// ---------------------------------------------------------------- fused dense GEMM + ReLU + LN
// C[M x 512] = LN(relu(A[M x K] @ Bt[512 x K]^T + bias)). BM=64, 256 thr,
// 4 waves x 128 cols, acc[4][8]. Software pipeline: A double-buffered in LDS
// (1 barrier/iter, drain overlapped with compute); B register-prefetched one
// 32-K chunk ahead, direct from global (L2-resident weights).
template <int K>
__global__ __launch_bounds__(256, 2) void gemm_ln(
    const u16* __restrict__ A, const u16* __restrict__ Bt,
    const float* __restrict__ bias, const float* __restrict__ lnsc,
    const float* __restrict__ lnbi, u16* __restrict__ C)
{
  constexpr int BK = 64, NI = K / BK;
  __shared__ __align__(16) u16 As[2][64 * BK];   // 2 x 8 KB
  __shared__ float redS[64][4];
  __shared__ float redSS[64][4];
  __shared__ float prm[1536];                     // bias | sc | bi
  const int tid = threadIdx.x;
  const int rowBase = blockIdx.x * 64;
  const int lane = tid & 63, wave = tid >> 6;
#pragma unroll
  for (int i = tid; i < 512; i += 256) {
    prm[i] = bias[i]; prm[512 + i] = lnsc[i]; prm[1024 + i] = lnbi[i];
  }
  u32 aOff[2];
#pragma unroll
  for (int r = 0; r < 2; ++r) {
    int row = r * 32 + (tid >> 3);
    aOff[r] = (u32)(rowBase + row) * (u32)K + (u32)(((tid & 7) ^ (row & 7)) * 8);
  }
  const int quad = lane >> 4, lm = lane & 15, l7 = lm & 7;
  const int wn = wave * 128;
  u32 bOff[8];
#pragma unroll
  for (int j = 0; j < 8; ++j)
    bOff[j] = (u32)(wn + j * 16 + lm) * (u32)K + (u32)(quad * 8);

  f32x4 acc[4][8] = {};

  // prologue: stage A(0), prefetch B(iter0, chunk0)
#pragma unroll
  for (int r = 0; r < 2; ++r)
    gll16(A + aOff[r], &As[0][r * 2048 + wave * 512]);
  bf16x8 bP[8];
#pragma unroll
  for (int j = 0; j < 8; ++j)
    bP[j] = *(const bf16x8*)(Bt + bOff[j]);
  __syncthreads();

  for (int i = 0; i < NI; ++i) {
    const u16* Ab = As[i & 1];
    if (i + 1 < NI) {
#pragma unroll
      for (int r = 0; r < 2; ++r)
        gll16(A + aOff[r] + (i + 1) * BK, &As[(i + 1) & 1][r * 2048 + wave * 512]);
    }
    // prefetch chunk1 of this iter, compute chunk0 with bP
    bf16x8 bN[8];
#pragma unroll
    for (int j = 0; j < 8; ++j)
      bN[j] = *(const bf16x8*)(Bt + bOff[j] + i * BK + 32);
    bf16x8 af[4];
#pragma unroll
    for (int i2 = 0; i2 < 4; ++i2)
      af[i2] = *(const bf16x8*)&Ab[(i2 * 16 + lm) * 64 + ((quad ^ l7) * 8)];
#pragma unroll
    for (int i2 = 0; i2 < 4; ++i2)
#pragma unroll
      for (int j = 0; j < 8; ++j)
        acc[i2][j] = __builtin_amdgcn_mfma_f32_16x16x32_bf16(af[i2], bP[j], acc[i2][j], 0, 0, 0);
    // prefetch next iter chunk0, compute chunk1 with bN
    if (i + 1 < NI) {
#pragma unroll
      for (int j = 0; j < 8; ++j)
        bP[j] = *(const bf16x8*)(Bt + bOff[j] + (i + 1) * BK);
    }
#pragma unroll
    for (int i2 = 0; i2 < 4; ++i2)
      af[i2] = *(const bf16x8*)&Ab[(i2 * 16 + lm) * 64 + (((quad + 4) ^ l7) * 8)];
#pragma unroll
    for (int i2 = 0; i2 < 4; ++i2)
#pragma unroll
      for (int j = 0; j < 8; ++j)
        acc[i2][j] = __builtin_amdgcn_mfma_f32_16x16x32_bf16(af[i2], bN[j], acc[i2][j], 0, 0, 0);
    __syncthreads();
  }

  // bias + relu + per-row partial stats (wave's 128 cols)
#pragma unroll
  for (int i2 = 0; i2 < 4; ++i2) {
#pragma unroll
    for (int r2 = 0; r2 < 4; ++r2) {
      float s = 0.f, ss = 0.f;
#pragma unroll
      for (int j = 0; j < 8; ++j) {
        float v = fmaxf(acc[i2][j][r2] + prm[wn + j * 16 + lm], 0.f);
        acc[i2][j][r2] = v;
        s += v; ss += v * v;
      }
#pragma unroll
      for (int o = 1; o < 16; o <<= 1) { s += __shfl_xor(s, o, 64); ss += __shfl_xor(ss, o, 64); }
      if (lm == 0) {
        int rowL = i2 * 16 + quad * 4 + r2;
        redS[rowL][wave] = s;
        redSS[rowL][wave] = ss;
      }
    }
  }
  __syncthreads();
#pragma unroll
  for (int i2 = 0; i2 < 4; ++i2) {
#pragma unroll
    for (int r2 = 0; r2 < 4; ++r2) {
      int rowL = i2 * 16 + quad * 4 + r2;
      float ts  = redS[rowL][0] + redS[rowL][1] + redS[rowL][2] + redS[rowL][3];
      float tss = redSS[rowL][0] + redSS[rowL][1] + redSS[rowL][2] + redSS[rowL][3];
      float m = ts * (1.f / 512.f);
      float var = tss * (1.f / 512.f) - m * m;
      float inv = rsqrtf(var + 1e-5f);
      size_t base = (size_t)(rowBase + rowL) * 512;
#pragma unroll
      for (int j = 0; j < 8; ++j) {
        int col = wn + j * 16 + lm;
        float y = (acc[i2][j][r2] - m) * inv * prm[512 + col] + prm[1024 + col];
        C[base + col] = f2b(y);
      }
    }
  }
}

// ---------------------------------------------------------------- fused role route + head (full)
// Per 32-row bucket tile: r1 = relu(obs_n[g] @ Wr0k + br0)      (256 -> 128)
//                         ea = relu(r1 @ Wr1k + br1) + e[g]     (128 -> 512)
//                         h0 = relu(ea @ Wh0k + bh0)            (512 -> 64, in LDS)
//                         h1 = relu(h0 @ Wh1k + bh1)            (64 -> 32, VALU)
//                         logits = mask(h1 @ Wh2k + bh2)        (32 -> 32, VALU) -> d_out
__global__ __launch_bounds__(256, 3) void route_head(
    const u16* __restrict__ obs_n, const u16* __restrict__ e,
    const u16* __restrict__ Wr0t, const float* __restrict__ br0,
    const u16* __restrict__ Wr1t, const float* __restrict__ br1,
    const u16* __restrict__ Wh0t, const float* __restrict__ bh0,
    const float* __restrict__ Wh1, const float* __restrict__ bh1,
    const float* __restrict__ Wh2, const float* __restrict__ bh2,
    const float* __restrict__ avail,
    const int* __restrict__ bucket, const int* __restrict__ baseArr,
    const int* __restrict__ cntArr, float* __restrict__ outLogits)
{
  // sm: [0,16384) A0(32x256)/e-tile(32x512); [16384,18560) h0s (32x68); r1 at [16384,20480) in stage0/1
  __shared__ __align__(16) u16 sm[20480];
  __shared__ float prm[704];        // br0 128 | br1 512 | bh0 64
  __shared__ float h1s[32 * 36];
  const int tid = threadIdx.x;

  int role = 0, rem = blockIdx.x, cnt;
  for (;;) {
    cnt = cntArr[role];
    int tiles = (cnt + 31) >> 5;
    if (rem < tiles) break;
    rem -= tiles;
    if (++role >= NROLE) return;
  }
  const int limit = cnt;
  const int rowBase = rem * 32;
  const int roleBase = baseArr[role];

  {
    const float* s0 = br0 + role * 128;
    const float* s1 = br1 + role * 512;
    const float* s2 = bh0 + role * 64;
    if (tid < 128) prm[tid] = s0[tid];
    for (int i = tid; i < 512; i += 256) prm[128 + i] = s1[i];
    if (tid < 64) prm[640 + tid] = s2[tid];
  }

  const int lane = tid & 63, wave = tid >> 6;
  const int quad = lane >> 4, lm = lane & 15, l7 = lm & 7;

  // ---- stage A0: gather 32 rows of obs_n (32x256) into LDS
#pragma unroll
  for (int r = 0; r < 4; ++r) {
    int lrow = r * 8 + (tid >> 5);
    int i = rowBase + lrow;
    if (i >= limit) i = rowBase;
    int grow = bucket[roleBase + i];
    gll16(obs_n + (u32)grow * 256u + (u32)((((tid & 31) ^ (lrow & 7)) * 8)),
          &sm[r * 2048 + wave * 512]);
  }
  __syncthreads();

  // ---- stage0: r1 = relu(A0 @ Wr0k^T + br0)   (N=128, wave covers 32 cols)
  const int wn0 = wave * 32;
  const u16* B0 = Wr0t + (size_t)role * 128 * 256;
  f32x4 acc0[2][2] = {};
#pragma unroll
  for (int kk = 0; kk < 256; kk += 32) {
    const int kc = kk >> 3;
    bf16x8 af[2], bf0[2];
#pragma unroll
    for (int i2 = 0; i2 < 2; ++i2)
      af[i2] = *(const bf16x8*)&sm[(i2 * 16 + lm) * 256 + (((quad + kc) ^ l7) * 8)];
#pragma unroll
    for (int j = 0; j < 2; ++j)
      bf0[j] = *(const bf16x8*)(B0 + (u32)(wn0 + j * 16 + lm) * 256u + (u32)(quad * 8 + kk));
#pragma unroll
    for (int i2 = 0; i2 < 2; ++i2)
#pragma unroll
      for (int j = 0; j < 2; ++j)
        acc0[i2][j] = __builtin_amdgcn_mfma_f32_16x16x32_bf16(af[i2], bf0[j], acc0[i2][j], 0, 0, 0);
  }
  u16* r1 = sm + 16384;
#pragma unroll
  for (int i2 = 0; i2 < 2; ++i2) {
#pragma unroll
    for (int r2 = 0; r2 < 4; ++r2) {
      int row = i2 * 16 + quad * 4 + r2;
#pragma unroll
      for (int j = 0; j < 2; ++j) {
        int col = wn0 + j * 16 + lm;
        float v = fmaxf(acc0[i2][j][r2] + prm[col], 0.f);
        r1[row * 128 + (((col >> 3) ^ (row & 7)) * 8) + (col & 7)] = f2b(v);
      }
    }
  }
  __syncthreads();

  // ---- stage1: ea = relu(r1 @ Wr1k^T + br1) + e[g]   (N=512, wave covers 128 cols)
  const int wn1 = wave * 128;
  const u16* B1 = Wr1t + (size_t)role * 512 * 128;
  f32x4 acc1[2][8] = {};
#pragma unroll
  for (int kk = 0; kk < 128; kk += 32) {
    const int kc = kk >> 3;
    bf16x8 af[2], bf1[8];
#pragma unroll
    for (int i2 = 0; i2 < 2; ++i2)
      af[i2] = *(const bf16x8*)&r1[(i2 * 16 + lm) * 128 + (((quad + kc) ^ l7) * 8)];
#pragma unroll
    for (int j = 0; j < 8; ++j)
      bf1[j] = *(const bf16x8*)(B1 + (u32)(wn1 + j * 16 + lm) * 128u + (u32)(quad * 8 + kk));
#pragma unroll
    for (int i2 = 0; i2 < 2; ++i2)
#pragma unroll
      for (int j = 0; j < 8; ++j)
        acc1[i2][j] = __builtin_amdgcn_mfma_f32_16x16x32_bf16(af[i2], bf1[j], acc1[i2][j], 0, 0, 0);
  }
#pragma unroll
  for (int i2 = 0; i2 < 2; ++i2) {
#pragma unroll
    for (int r2 = 0; r2 < 4; ++r2) {
      int row = i2 * 16 + quad * 4 + r2;
      int i = rowBase + row;
      int ic = (i < limit) ? i : (limit - 1);
      u32 grow = (u32)bucket[roleBase + ic];
#pragma unroll
      for (int j = 0; j < 8; ++j) {
        int col = wn1 + j * 16 + lm;
        float v = fmaxf(acc1[i2][j][r2] + prm[128 + col], 0.f) + b2f(e[(size_t)grow * 512 + col]);
        sm[row * 512 + (((col >> 3) ^ (row & 7)) * 8) + (col & 7)] = f2b(v);
      }
    }
  }
  __syncthreads();

  // ---- stage2: h0 = relu(ea @ Wh0k^T + bh0)   (N=64, wave covers 16 cols) -> LDS
  const int wn2 = wave * 16;
  const u16* B2 = Wh0t + (size_t)role * 64 * 512;
  f32x4 acc2[2] = {};
#pragma unroll
  for (int kk = 0; kk < 512; kk += 32) {
    const int kc = kk >> 3;
    bf16x8 af[2], bf2;
#pragma unroll
    for (int i2 = 0; i2 < 2; ++i2)
      af[i2] = *(const bf16x8*)&sm[(i2 * 16 + lm) * 512 + (((quad + kc) ^ l7) * 8)];
    bf2 = *(const bf16x8*)(B2 + (u32)(wn2 + lm) * 512u + (u32)(quad * 8 + kk));
#pragma unroll
    for (int i2 = 0; i2 < 2; ++i2)
      acc2[i2] = __builtin_amdgcn_mfma_f32_16x16x32_bf16(af[i2], bf2, acc2[i2], 0, 0, 0);
  }
  u16* h0s = sm + 16384;   // 32 rows x stride 68 (r1 region, dead now)
#pragma unroll
  for (int i2 = 0; i2 < 2; ++i2) {
#pragma unroll
    for (int r2 = 0; r2 < 4; ++r2) {
      int row = i2 * 16 + quad * 4 + r2;
      int col = wn2 + lm;
      h0s[row * 68 + col] = f2b(fmaxf(acc2[i2][r2] + prm[640 + col], 0.f));
    }
  }
  __syncthreads();

  // ---- stage3: per-thread tail. thread t -> row r=t>>3, 4 cols n0=(t&7)*4
  {
    const int r = tid >> 3;
    const int n0 = (tid & 7) * 4;
    const bool valid = (rowBase + r) < limit;
    const float* W1k = Wh1 + (size_t)role * 64 * 32;
    const float* W2k = Wh2 + (size_t)role * 32 * 32;
    float4 a1 = *(const float4*)(bh1 + role * 32 + n0);
#pragma unroll 8
    for (int j = 0; j < 64; ++j) {
      float hj = b2f(h0s[r * 68 + j]);
      float4 wv = *(const float4*)(W1k + j * 32 + n0);
      a1.x += hj * wv.x; a1.y += hj * wv.y; a1.z += hj * wv.z; a1.w += hj * wv.w;
    }
    h1s[r * 36 + n0 + 0] = fmaxf(a1.x, 0.f);
    h1s[r * 36 + n0 + 1] = fmaxf(a1.y, 0.f);
    h1s[r * 36 + n0 + 2] = fmaxf(a1.z, 0.f);
    h1s[r * 36 + n0 + 3] = fmaxf(a1.w, 0.f);
    __syncthreads();
    float4 a2 = *(const float4*)(bh2 + role * 32 + n0);
#pragma unroll 8
    for (int n = 0; n < 32; ++n) {
      float hn = h1s[r * 36 + n];
      float4 wv = *(const float4*)(W2k + n * 32 + n0);
      a2.x += hn * wv.x; a2.y += hn * wv.y; a2.z += hn * wv.z; a2.w += hn * wv.w;
    }
    if (valid) {
      int g = bucket[roleBase + rowBase + r];
      float4 av = *(const float4*)(avail + (size_t)g * 32 + n0);
      float4 o;
      o.x = (av.x > 0.5f) ? a2.x : -1e10f;
      o.y = (av.y > 0.5f) ? a2.y : -1e10f;
      o.z = (av.z > 0.5f) ? a2.z : -1e10f;
      o.w = (av.w > 0.5f) ? a2.w : -1e10f;
      *(float4*)(outLogits + (size_t)g * 32 + n0) = o;
    }
  }
}

// ---------------------------------------------------------------- launcher
extern "C" void kernel_launch(void* const* d_in, const int* in_sizes, int n_in,
                              void* d_out, int out_size, void* d_ws, size_t ws_size,
                              hipStream_t stream)
{
  const float* rnn  = (const float*)d_in[0];
  const float* obs  = (const float*)d_in[1];
  const float* avail= (const float*)d_in[3];
  const int*   rid  = (const int*)d_in[4];
  const float* fn_s = (const float*)d_in[5];
  const float* fn_b = (const float*)d_in[6];
  const float* W0   = (const float*)d_in[7];
  const float* b0   = (const float*)d_in[8];
  const float* ln0s = (const float*)d_in[9];
  const float* ln0b = (const float*)d_in[10];
  const float* W1   = (const float*)d_in[11];
  const float* b1   = (const float*)d_in[12];
  const float* ln1s = (const float*)d_in[13];
  const float* ln1b = (const float*)d_in[14];
  const float* Wr0  = (const float*)d_in[15];
  const float* br0  = (const float*)d_in[16];
  const float* Wr1  = (const float*)d_in[17];
  const float* br1  = (const float*)d_in[18];
  const float* Wh0  = (const float*)d_in[19];
  const float* bh0  = (const float*)d_in[20];
  const float* Wh1  = (const float*)d_in[21];
  const float* bh1  = (const float*)d_in[22];
  const float* Wh2  = (const float*)d_in[23];
  const float* bh2  = (const float*)d_in[24];

  const int ROWS = 32768;

  char* w = (char*)d_ws;
  auto carve = [&](size_t bytes) { char* p = w; w += (bytes + 255) & ~(size_t)255; return p; };
  u16* obs_n  = (u16*)carve((size_t)ROWS * 256 * 2);
  u16* bufA   = (u16*)carve((size_t)ROWS * 512 * 2);   // e0
  u16* bufB   = (u16*)carve((size_t)ROWS * 512 * 2);   // e
  u16* W0t    = (u16*)carve((size_t)512 * 256 * 2);
  u16* W1t    = (u16*)carve((size_t)512 * 512 * 2);
  u16* Wr0t   = (u16*)carve((size_t)6 * 128 * 256 * 2);
  u16* Wr1t   = (u16*)carve((size_t)6 * 512 * 128 * 2);
  u16* Wh0t   = (u16*)carve((size_t)6 * 64 * 512 * 2);
  int* bucket = (int*)carve((size_t)ROWS * 4);
  int* blkCnt = (int*)carve((size_t)128 * NROLE * 4);
  int* blkBase= (int*)carve((size_t)128 * NROLE * 4);
  int* baseArr= (int*)carve(256);
  int* cntArr = (int*)carve(256);

  float* outLogits = (float*)d_out + (size_t)1024 * 512;

  hipMemcpyAsync(d_out, rnn, (size_t)1024 * 512 * 4, hipMemcpyDeviceToDevice, stream);

  transpose_all<<<1152, 256, 0, stream>>>(W0, W1, Wr0, Wr1, Wh0, W0t, W1t, Wr0t, Wr1t, Wh0t);

  ln_f32_256<<<8192, 256, 0, stream>>>(obs, fn_s, fn_b, obs_n, ROWS);

  role_count<<<128, 256, 0, stream>>>(rid, blkCnt);
  role_scan<<<1, 256, 0, stream>>>(blkCnt, blkBase, baseArr, cntArr);
  role_fill<<<128, 256, 0, stream>>>(rid, blkBase, bucket);

  // base MLP, LN fused + software-pipelined
  gemm_ln<256><<<512, 256, 0, stream>>>(obs_n, W0t, b0, ln0s, ln0b, bufA);
  gemm_ln<512><<<512, 256, 0, stream>>>(bufA, W1t, b1, ln1s, ln1b, bufB);

  // fused role route + full head (writes final logits)
  route_head<<<1029, 256, 0, stream>>>(obs_n, bufB, Wr0t, br0, Wr1t, br1, Wh0t, bh0,
                                       Wh1, bh1, Wh2, bh2, avail,
                                       bucket, baseArr, cntArr, outLogits);
}